// Round 14
// baseline (453.881 us; speedup 1.0000x reference)
//
#include <hip/hip_runtime.h>

// RNN-T joint: log_softmax(fc2(tanh(fc1(cat(enc,dec))))), fused.
// B=4, M=256, N=128, D=512, C=1024, JOINT=1024.
// ws: heb f32 [1024][512] (he+b1) | hdb bf16 [512][512] | w2p i8 512KB | scF f32[1024]
//
// R14 = persistent R12: 8-wave blocks, 256 regs/wave (__launch_bounds__(512,2),
// 1 block/CU), 16 items of 32 rows each. Store-drain hidden by FIFO ordering:
// next item's stage loads issue BEFORE this item's nt stores, and barriers are
// raw s_barrier + lgkmcnt only (no vmcnt drain). 4-deep A prefetch (regs now
// available). R6/R8 persistent failures were 128-reg spills + cached-store L2
// thrash; both removed (256 cap, nt stores).

typedef __attribute__((ext_vector_type(8))) __bf16 bf16x8;
typedef __attribute__((ext_vector_type(8))) unsigned short u16x8;
typedef __attribute__((ext_vector_type(4))) float f32x4;
typedef __attribute__((ext_vector_type(4))) int i32x4;
typedef __attribute__((ext_vector_type(16))) int i32x16;

__device__ __forceinline__ float tanh_fast(float x) {
    float e = __expf(2.0f * x);
    return 1.0f - 2.0f / (e + 1.0f);
}
__device__ __forceinline__ float bf2f(unsigned short u) {
    return __builtin_bit_cast(float, (unsigned)u << 16);
}
__device__ __forceinline__ unsigned short f2bf(float f) {
    return __builtin_bit_cast(unsigned short, (__bf16)f);
}
__device__ __forceinline__ int pack4(float a, float b, float c, float d, float s) {
    int q0 = __float2int_rn(a * s) & 255;
    int q1 = __float2int_rn(b * s) & 255;
    int q2 = __float2int_rn(c * s) & 255;
    int q3 = __float2int_rn(d * s) & 255;
    return q0 | (q1 << 8) | (q2 << 16) | (q3 << 24);
}

// barrier that does NOT drain vmcnt (keeps nt stores in flight)
__device__ __forceinline__ void barrier_lgkm() {
    asm volatile("s_waitcnt lgkmcnt(0)" ::: "memory");
    __builtin_amdgcn_s_barrier();
    asm volatile("" ::: "memory");
}

// k_prep-only LDS swizzle
__device__ __forceinline__ int swz(int row, int kbyte) {
    return row * 1024 + (kbyte ^ ((row & 7) << 4));
}

__device__ __forceinline__ bf16x8 cvt8(float4 a, float4 b) {
    bf16x8 r;
    r[0] = (__bf16)a.x; r[1] = (__bf16)a.y; r[2] = (__bf16)a.z; r[3] = (__bf16)a.w;
    r[4] = (__bf16)b.x; r[5] = (__bf16)b.y; r[6] = (__bf16)b.z; r[7] = (__bf16)b.w;
    return r;
}

// ---------------------------------------------------------------------------
// Prep (validated R12): blocks 0..31 -> heb = enc@w1enc^T + b1 (f32, 32 rows),
// 32..47 -> hdb = bf16(dec@w1dec^T), 48..63 -> w2 quantize+pack (i8) + scF.
// ---------------------------------------------------------------------------
__global__ __launch_bounds__(512) void k_prep(
    const float* __restrict__ enc, const float* __restrict__ dec,
    const float* __restrict__ w1, const float* __restrict__ b1,
    const float* __restrict__ w2,
    float* __restrict__ heb, unsigned short* __restrict__ hdb,
    char* __restrict__ w2p, float* __restrict__ scF)
{
    const int bid = blockIdx.x, tid = threadIdx.x;
    const int lane = tid & 63, wid = tid >> 6;

    if (bid >= 48) {  // quantize + pack w2 -> w2p (i8), write scF
        int W = (bid - 48) * 8 + wid;
        #pragma unroll
        for (int j = 0; j < 8; ++j) {
            int c = W * 8 + j;
            const float4* s = (const float4*)(w2 + c * 512 + lane * 8);
            float4 a = s[0], bq = s[1];
            float m = fmaxf(fmaxf(fabsf(a.x), fabsf(a.y)), fmaxf(fabsf(a.z), fabsf(a.w)));
            m = fmaxf(m, fmaxf(fmaxf(fabsf(bq.x), fabsf(bq.y)),
                               fmaxf(fabsf(bq.z), fabsf(bq.w))));
            #pragma unroll
            for (int d = 1; d < 64; d <<= 1) m = fmaxf(m, __shfl_xor(m, d));
            float r = 127.f / m;
            int d0 = pack4(a.x, a.y, a.z, a.w, r);
            int d1 = pack4(bq.x, bq.y, bq.z, bq.w, r);
            int t = lane >> 2, lhc = (lane >> 1) & 1, off = lane & 1;
            char* dst = w2p + ((size_t)((c >> 5) * 16 + t)) * 1024
                        + lhc * 512 + (c & 31) * 16 + off * 8;
            *(unsigned long long*)dst =
                (unsigned)d0 | ((unsigned long long)(unsigned)d1 << 32);
            if (lane == 0) scF[c] = m / 16129.f;   // 127*127
        }
        return;
    }

    __shared__ uint4 ldsq[2048];
    char* lds = (char*)ldsq;

    const bool ishe = bid < 32;
    const int r0 = (ishe ? bid : bid - 32) * 32;
    const float* src = (ishe ? enc : dec) + r0 * 512;
    const float* wsrc = w1 + (ishe ? 0 : 512);

    #pragma unroll
    for (int j = 0; j < 4; j++) {
        int row = wid * 4 + j;
        const float4* p = (const float4*)(src + row * 512 + lane * 8);
        *(bf16x8*)(lds + swz(row, lane * 16)) = cvt8(p[0], p[1]);
    }
    __syncthreads();

    const int lr = lane & 15, lg = lane >> 4;
    f32x4 acc[2][4];
    #pragma unroll
    for (int rt = 0; rt < 2; rt++)
        #pragma unroll
        for (int ct = 0; ct < 4; ct++)
            acc[rt][ct] = f32x4{0.f, 0.f, 0.f, 0.f};

    #pragma unroll 1
    for (int ks = 0; ks < 512; ks += 32) {
        bf16x8 af[2];
        #pragma unroll
        for (int rt = 0; rt < 2; rt++)
            af[rt] = *(const bf16x8*)(lds + swz(rt * 16 + lr, ks * 2 + lg * 16));
        #pragma unroll
        for (int ct = 0; ct < 4; ct++) {
            int col = wid * 64 + ct * 16 + lr;
            const float4* wp = (const float4*)(wsrc + col * 1024 + ks + lg * 8);
            bf16x8 bfr = cvt8(wp[0], wp[1]);
            #pragma unroll
            for (int rt = 0; rt < 2; rt++)
                acc[rt][ct] = __builtin_amdgcn_mfma_f32_16x16x32_bf16(af[rt], bfr, acc[rt][ct], 0, 0, 0);
        }
    }

    if (ishe) {
        float b1v[4];
        #pragma unroll
        for (int ct = 0; ct < 4; ct++) b1v[ct] = b1[wid * 64 + ct * 16 + lr];
        #pragma unroll
        for (int rt = 0; rt < 2; rt++)
            #pragma unroll
            for (int ct = 0; ct < 4; ct++)
                #pragma unroll
                for (int reg = 0; reg < 4; reg++)
                    heb[(r0 + rt * 16 + lg * 4 + reg) * 512 + wid * 64 + ct * 16 + lr] =
                        acc[rt][ct][reg] + b1v[ct];
    } else {
        #pragma unroll
        for (int rt = 0; rt < 2; rt++)
            #pragma unroll
            for (int ct = 0; ct < 4; ct++)
                #pragma unroll
                for (int reg = 0; reg < 4; reg++)
                    hdb[(r0 + rt * 16 + lg * 4 + reg) * 512 + wid * 64 + ct * 16 + lr] =
                        f2bf(acc[rt][ct][reg]);
    }
}

// ---------------------------------------------------------------------------
// issue stage loads for one item into held registers (no waits here)
// ---------------------------------------------------------------------------
__device__ __forceinline__ void issue_stage(
    int item, const float* heb, const unsigned short* hdb,
    int w, int l5, int lh, u16x8 (&Hv)[2][2], float4 (&Ev)[2][4])
{
    const int bm = item >> 2, nq = item & 3, bq = bm >> 8;
    const float* ep = heb + (size_t)bm * 512;
    #pragma unroll
    for (int it = 0; it < 2; ++it) {
        int k0 = (w * 2 + it) * 32 + lh * 16;
        const unsigned short* hb = hdb + (size_t)(bq * 128 + nq * 32 + l5) * 512 + k0;
        Hv[it][0] = *(const u16x8*)hb;
        Hv[it][1] = *(const u16x8*)(hb + 8);
        Ev[it][0] = *(const float4*)(ep + k0);
        Ev[it][1] = *(const float4*)(ep + k0 + 4);
        Ev[it][2] = *(const float4*)(ep + k0 + 8);
        Ev[it][3] = *(const float4*)(ep + k0 + 12);
    }
}

// ---------------------------------------------------------------------------
// Main: PERSISTENT block = 8 waves (512 thr), 16 items of 32 rows x 1024
// classes each. mfma_i32_32x32x32_i8, swapped (A = w2 classes, B = hid rows):
// lane holds row n = lane&31, classes w*128 + ct*32 + 8q + 4*(lane>>5) + i.
// Per item: stage-write (from pre-issued loads) -> lgkm barrier -> K-loop
// (A 4-deep reg prefetch from L2) -> dequant+b2 -> stats -> lgkm barrier ->
// logZ -> issue NEXT item's stage loads -> fence -> transpose (2KB/wave in
// dead hid buf) + nt stores. Stores drain under next item's stage+K.
// ---------------------------------------------------------------------------
__global__ __launch_bounds__(512, 2) void k_main(
    const float* __restrict__ heb, const unsigned short* __restrict__ hdb,
    const float* __restrict__ b2, const char* __restrict__ w2p,
    const float* __restrict__ scF, float* __restrict__ out)
{
    __shared__ uint4 hidq[2][1024];       // 2 x 16 KB hid_q buffers
    __shared__ float redm[32][8];
    __shared__ float reds[32][8];

    // XCD-bijective remap (256 % 8 == 0): 32 consecutive blocks per XCD.
    const int bid = ((blockIdx.x & 7) << 5) | (blockIdx.x >> 3);
    const int tid = threadIdx.x;
    const int lane = tid & 63, w = tid >> 6;
    const int l5 = lane & 31, lh = lane >> 5;

    const char* pw = w2p + ((size_t)w << 16) + (lane << 4);
    const int rr = lane >> 2, c4 = lane & 3;

    u16x8 Hv[2][2];
    float4 Ev[2][4];
    issue_stage(bid * 16, heb, hdb, w, l5, lh, Hv, Ev);

    #pragma unroll 1
    for (int j = 0; j < 16; ++j) {
        const int item = bid * 16 + j;
        const int bm = item >> 2, nq = item & 3;
        char* hid = (char*)&hidq[j & 1][0];

        // ---- stage write: tanh+pack from held regs, frag-linear ----
        #pragma unroll
        for (int it = 0; it < 2; ++it) {
            int t = w * 2 + it;
            i32x4 o;
            o[0] = pack4(tanh_fast(bf2f(Hv[it][0][0]) + Ev[it][0].x),
                         tanh_fast(bf2f(Hv[it][0][1]) + Ev[it][0].y),
                         tanh_fast(bf2f(Hv[it][0][2]) + Ev[it][0].z),
                         tanh_fast(bf2f(Hv[it][0][3]) + Ev[it][0].w), 127.f);
            o[1] = pack4(tanh_fast(bf2f(Hv[it][0][4]) + Ev[it][1].x),
                         tanh_fast(bf2f(Hv[it][0][5]) + Ev[it][1].y),
                         tanh_fast(bf2f(Hv[it][0][6]) + Ev[it][1].z),
                         tanh_fast(bf2f(Hv[it][0][7]) + Ev[it][1].w), 127.f);
            o[2] = pack4(tanh_fast(bf2f(Hv[it][1][0]) + Ev[it][2].x),
                         tanh_fast(bf2f(Hv[it][1][1]) + Ev[it][2].y),
                         tanh_fast(bf2f(Hv[it][1][2]) + Ev[it][2].z),
                         tanh_fast(bf2f(Hv[it][1][3]) + Ev[it][2].w), 127.f);
            o[3] = pack4(tanh_fast(bf2f(Hv[it][1][4]) + Ev[it][3].x),
                         tanh_fast(bf2f(Hv[it][1][5]) + Ev[it][3].y),
                         tanh_fast(bf2f(Hv[it][1][6]) + Ev[it][3].z),
                         tanh_fast(bf2f(Hv[it][1][7]) + Ev[it][3].w), 127.f);
            *(i32x4*)(hid + t * 1024 + lane * 16) = o;
        }
        barrier_lgkm();

        // ---- K-loop: w2 (A) from L2, 4-deep slot-reuse prefetch; hid_q (B) LDS ----
        const char* la = hid + (lane << 4);

        i32x16 acc[4];
        #pragma unroll
        for (int ct = 0; ct < 4; ct++)
            #pragma unroll
            for (int r = 0; r < 16; r++)
                acc[ct][r] = 0;

        i32x4 aw[4][4];
        #pragma unroll
        for (int s = 0; s < 4; s++)
            #pragma unroll
            for (int ct = 0; ct < 4; ct++)
                aw[s][ct] = *(const i32x4*)(pw + ct * 16384 + s * 1024);
        i32x4 h0 = *(const i32x4*)(la);

        #pragma unroll
        for (int kt = 0; kt < 16; ++kt) {
            i32x4 hn = h0;
            if (kt < 15) hn = *(const i32x4*)(la + (kt + 1) * 1024);
            __builtin_amdgcn_s_setprio(1);
            #pragma unroll
            for (int ct = 0; ct < 4; ct++)
                acc[ct] = __builtin_amdgcn_mfma_i32_32x32x32_i8(
                    aw[kt & 3][ct], h0, acc[ct], 0, 0, 0);
            __builtin_amdgcn_s_setprio(0);
            if (kt < 12) {
                #pragma unroll
                for (int ct = 0; ct < 4; ct++)
                    aw[kt & 3][ct] = *(const i32x4*)(pw + ct * 16384 + (kt + 4) * 1024);
            }
            h0 = hn;
        }

        // ---- dequant + b2 (f32 bits written back in place) ----
        #pragma unroll
        for (int ct = 0; ct < 4; ct++)
            #pragma unroll
            for (int q = 0; q < 4; q++) {
                const int base = w * 128 + ct * 32 + q * 8 + lh * 4;
                float4 sc4 = *(const float4*)(scF + base);
                float4 b24 = *(const float4*)(b2 + base);
                acc[ct][q * 4 + 0] = __float_as_int((float)acc[ct][q * 4 + 0] * sc4.x + b24.x);
                acc[ct][q * 4 + 1] = __float_as_int((float)acc[ct][q * 4 + 1] * sc4.y + b24.y);
                acc[ct][q * 4 + 2] = __float_as_int((float)acc[ct][q * 4 + 2] * sc4.z + b24.z);
                acc[ct][q * 4 + 3] = __float_as_int((float)acc[ct][q * 4 + 3] * sc4.w + b24.w);
            }

        // ---- row stats: 64 values in-lane (row n = l5), merge lane^32 ----
        float mx = -3.4e38f;
        #pragma unroll
        for (int ct = 0; ct < 4; ct++)
            #pragma unroll
            for (int r = 0; r < 16; r++)
                mx = fmaxf(mx, __int_as_float(acc[ct][r]));
        float sv = 0.f;
        #pragma unroll
        for (int ct = 0; ct < 4; ct++)
            #pragma unroll
            for (int r = 0; r < 16; r++)
                sv += __expf(__int_as_float(acc[ct][r]) - mx);
        {
            float mo = __shfl_xor(mx, 32), so = __shfl_xor(sv, 32);
            float mn = fmaxf(mx, mo);
            sv = sv * __expf(mx - mn) + so * __expf(mo - mn);
            mx = mn;
        }
        if (lh == 0) { redm[l5][w] = mx; reds[l5][w] = sv; }
        barrier_lgkm();    // hid dead after this -> transpose buffer

        float logZ;
        {
            float4 ma = *(const float4*)&redm[l5][0];
            float4 mb = *(const float4*)&redm[l5][4];
            float4 sa = *(const float4*)&reds[l5][0];
            float4 sb = *(const float4*)&reds[l5][4];
            float M = fmaxf(fmaxf(fmaxf(ma.x, ma.y), fmaxf(ma.z, ma.w)),
                            fmaxf(fmaxf(mb.x, mb.y), fmaxf(mb.z, mb.w)));
            float S = sa.x * __expf(ma.x - M) + sa.y * __expf(ma.y - M)
                    + sa.z * __expf(ma.z - M) + sa.w * __expf(ma.w - M)
                    + sb.x * __expf(mb.x - M) + sb.y * __expf(mb.y - M)
                    + sb.z * __expf(mb.z - M) + sb.w * __expf(mb.w - M);
            logZ = M + __logf(S);
        }

        // ---- issue NEXT item's stage loads BEFORE stores (vmcnt FIFO:
        //      loads older than stores -> tanh(j+1) won't wait on the drain)
        if (j < 15)
            issue_stage(item + 1, heb, hdb, w, l5, lh, Hv, Ev);
        asm volatile("" ::: "memory");   // pin load-before-store issue order

        // ---- transpose epilogue: 2 KB/wave region in dead hid buf ----
        char* myr = hid + w * 2048;
        const size_t rowbase = (size_t)bm * 128 + nq * 32;
        #pragma unroll
        for (int ct = 0; ct < 4; ct++)
            #pragma unroll
            for (int qh = 0; qh < 2; qh++) {
                #pragma unroll
                for (int qi = 0; qi < 2; qi++) {
                    int q = qh * 2 + qi;
                    f32x4 o;
                    o[0] = __int_as_float(acc[ct][q * 4 + 0]) - logZ;
                    o[1] = __int_as_float(acc[ct][q * 4 + 1]) - logZ;
                    o[2] = __int_as_float(acc[ct][q * 4 + 2]) - logZ;
                    o[3] = __int_as_float(acc[ct][q * 4 + 3]) - logZ;
                    *(f32x4*)(myr + l5 * 64 + ((qi * 32 + lh * 16) ^ ((l5 & 3) << 4))) = o;
                }
                #pragma unroll
                for (int rh = 0; rh < 2; rh++) {
                    int row = rh * 16 + rr;
                    f32x4 v = *(const f32x4*)(myr + row * 64 +
                                              ((c4 * 16) ^ ((row & 3) << 4)));
                    __builtin_nontemporal_store(v,
                        (f32x4*)(out + (rowbase + row) * 1024 + w * 128 + ct * 32 +
                                 qh * 16 + c4 * 4));
                }
            }
    }
}

extern "C" void kernel_launch(void* const* d_in, const int* in_sizes, int n_in,
                              void* d_out, int out_size, void* d_ws, size_t ws_size,
                              hipStream_t stream) {
    const float* enc = (const float*)d_in[0];
    const float* dec = (const float*)d_in[1];
    const float* w1  = (const float*)d_in[2];
    const float* b1  = (const float*)d_in[3];
    const float* w2  = (const float*)d_in[4];
    const float* b2  = (const float*)d_in[5];

    float* heb = (float*)d_ws;                                   // 2 MB
    unsigned short* hdb = (unsigned short*)(heb + 1024 * 512);   // 0.5 MB
    char* w2p = (char*)(hdb + 512 * 512);                        // 512 KB
    float* scF = (float*)(w2p + 512 * 1024);                     // 4 KB

    k_prep<<<64, 512, 0, stream>>>(enc, dec, w1, b1, w2, heb, hdb, w2p, scF);
    k_main<<<256, 512, 0, stream>>>(heb, hdb, b2, w2p, scF, (float*)d_out);
}

// Round 15
// 219.580 us; speedup vs baseline: 2.0670x; 2.0670x over previous
//
#include <hip/hip_runtime.h>

// RNN-T joint: log_softmax(fc2(tanh(fc1(cat(enc,dec))))), fused.
// B=4, M=256, N=128, D=512, C=1024, JOINT=1024.
// ws: heb f32 [1024][512] (he+b1) | hdb bf16 [512][512] | w2p i8 512KB | scF f32[1024]
//
// R15 = R12 (best, 223us: 32-row x 1024-col blocks, 8 waves, i8 swapped MFMA,
// 2-deep A prefetch, transpose epilogue, nt stores, XCD swizzle) with two
// zero-register-cost fixes:
//  1. hdb staging de-scattered: coalesced hdb -> raw LDS, then fragment
//     slices read from LDS (was a 32-segment 1KB-stride scatter, 4x L2
//     over-fetch).
//  2. k_prep widened 64 -> 128 blocks (16 GEMM rows/block).

typedef __attribute__((ext_vector_type(8))) __bf16 bf16x8;
typedef __attribute__((ext_vector_type(8))) unsigned short u16x8;
typedef __attribute__((ext_vector_type(4))) float f32x4;
typedef __attribute__((ext_vector_type(4))) int i32x4;
typedef __attribute__((ext_vector_type(16))) int i32x16;

__device__ __forceinline__ float tanh_fast(float x) {
    float e = __expf(2.0f * x);
    return 1.0f - 2.0f / (e + 1.0f);
}
__device__ __forceinline__ float bf2f(unsigned short u) {
    return __builtin_bit_cast(float, (unsigned)u << 16);
}
__device__ __forceinline__ unsigned short f2bf(float f) {
    return __builtin_bit_cast(unsigned short, (__bf16)f);
}
__device__ __forceinline__ int pack4(float a, float b, float c, float d, float s) {
    int q0 = __float2int_rn(a * s) & 255;
    int q1 = __float2int_rn(b * s) & 255;
    int q2 = __float2int_rn(c * s) & 255;
    int q3 = __float2int_rn(d * s) & 255;
    return q0 | (q1 << 8) | (q2 << 16) | (q3 << 24);
}

// LDS swizzle for [rows][1KB] tiles: XOR row&7 into byte bits 4-6
__device__ __forceinline__ int swz(int row, int kbyte) {
    return row * 1024 + (kbyte ^ ((row & 7) << 4));
}

__device__ __forceinline__ bf16x8 cvt8(float4 a, float4 b) {
    bf16x8 r;
    r[0] = (__bf16)a.x; r[1] = (__bf16)a.y; r[2] = (__bf16)a.z; r[3] = (__bf16)a.w;
    r[4] = (__bf16)b.x; r[5] = (__bf16)b.y; r[6] = (__bf16)b.z; r[7] = (__bf16)b.w;
    return r;
}

// ---------------------------------------------------------------------------
// Prep (widened): blocks 0..63  -> heb = enc@w1enc^T + b1 (f32), 16 rows each
//                 blocks 64..95 -> hdb = bf16(dec@w1dec^T), 16 rows each
//                 blocks 96..127-> w2 quantize+pack (i8, 4 classes/wave) + scF
// w2p chunk for (class c, kt32 t): region ((c>>5)*16 + t)*1024, byte
// lh*512 + (c&31)*16; consumer lane l = lh*32 + (c&31) reads l*16.
// ---------------------------------------------------------------------------
__global__ __launch_bounds__(512) void k_prep(
    const float* __restrict__ enc, const float* __restrict__ dec,
    const float* __restrict__ w1, const float* __restrict__ b1,
    const float* __restrict__ w2,
    float* __restrict__ heb, unsigned short* __restrict__ hdb,
    char* __restrict__ w2p, float* __restrict__ scF)
{
    const int bid = blockIdx.x, tid = threadIdx.x;
    const int lane = tid & 63, wid = tid >> 6;

    if (bid >= 96) {  // quantize + pack w2 -> w2p (i8), write scF
        int W = (bid - 96) * 8 + wid;            // 0..255
        #pragma unroll
        for (int j = 0; j < 4; ++j) {
            int c = W * 4 + j;
            const float4* s = (const float4*)(w2 + c * 512 + lane * 8);
            float4 a = s[0], bq = s[1];
            float m = fmaxf(fmaxf(fabsf(a.x), fabsf(a.y)), fmaxf(fabsf(a.z), fabsf(a.w)));
            m = fmaxf(m, fmaxf(fmaxf(fabsf(bq.x), fabsf(bq.y)),
                               fmaxf(fabsf(bq.z), fabsf(bq.w))));
            #pragma unroll
            for (int d = 1; d < 64; d <<= 1) m = fmaxf(m, __shfl_xor(m, d));
            float r = 127.f / m;
            int d0 = pack4(a.x, a.y, a.z, a.w, r);
            int d1 = pack4(bq.x, bq.y, bq.z, bq.w, r);
            int t = lane >> 2, lhc = (lane >> 1) & 1, off = lane & 1;
            char* dst = w2p + ((size_t)((c >> 5) * 16 + t)) * 1024
                        + lhc * 512 + (c & 31) * 16 + off * 8;
            *(unsigned long long*)dst =
                (unsigned)d0 | ((unsigned long long)(unsigned)d1 << 32);
            if (lane == 0) scF[c] = m / 16129.f;   // 127*127
        }
        return;
    }

    __shared__ uint4 ldsq[1024];           // 16 KB A tile (16 rows x 512 k bf16)
    char* lds = (char*)ldsq;

    const bool ishe = bid < 64;
    const int r0 = (ishe ? bid : bid - 64) * 16;
    const float* src = (ishe ? enc : dec) + r0 * 512;
    const float* wsrc = w1 + (ishe ? 0 : 512);

    #pragma unroll
    for (int j = 0; j < 2; j++) {
        int row = wid * 2 + j;
        const float4* p = (const float4*)(src + row * 512 + lane * 8);
        *(bf16x8*)(lds + swz(row, lane * 16)) = cvt8(p[0], p[1]);
    }
    __syncthreads();

    const int lr = lane & 15, lg = lane >> 4;
    f32x4 acc[4];
    #pragma unroll
    for (int ct = 0; ct < 4; ct++)
        acc[ct] = f32x4{0.f, 0.f, 0.f, 0.f};

    #pragma unroll 1
    for (int ks = 0; ks < 512; ks += 32) {
        bf16x8 af = *(const bf16x8*)(lds + swz(lr, ks * 2 + lg * 16));
        #pragma unroll
        for (int ct = 0; ct < 4; ct++) {
            int col = wid * 64 + ct * 16 + lr;
            const float4* wp = (const float4*)(wsrc + col * 1024 + ks + lg * 8);
            bf16x8 bfr = cvt8(wp[0], wp[1]);
            acc[ct] = __builtin_amdgcn_mfma_f32_16x16x32_bf16(af, bfr, acc[ct], 0, 0, 0);
        }
    }

    if (ishe) {
        float b1v[4];
        #pragma unroll
        for (int ct = 0; ct < 4; ct++) b1v[ct] = b1[wid * 64 + ct * 16 + lr];
        #pragma unroll
        for (int ct = 0; ct < 4; ct++)
            #pragma unroll
            for (int reg = 0; reg < 4; reg++)
                heb[(r0 + lg * 4 + reg) * 512 + wid * 64 + ct * 16 + lr] =
                    acc[ct][reg] + b1v[ct];
    } else {
        #pragma unroll
        for (int ct = 0; ct < 4; ct++)
            #pragma unroll
            for (int reg = 0; reg < 4; reg++)
                hdb[(r0 + lg * 4 + reg) * 512 + wid * 64 + ct * 16 + lr] =
                    f2bf(acc[ct][reg]);
    }
}

// ---------------------------------------------------------------------------
// Main: block = 32 rows (one (b,m), 32 n's) x 1024 classes, 8 waves.
// mfma_i32_32x32x32_i8, swapped (A = w2 classes, B = hid rows):
//   lane holds row n = lane&31; classes w*128 + ct*32 + 8q + 4*(lane>>5) + i.
// Stage: coalesced hdb -> raw LDS (full 64B lines), fragment slices read from
// LDS (swizzled), tanh+pack in regs, frag-linear write. K-loop: A 2-deep
// slot-reuse prefetch from L2. Epilogue: dequant+b2 in place, in-lane stats,
// per-wave LDS transpose, full-line nt stores.
// ---------------------------------------------------------------------------
__global__ __launch_bounds__(512, 4) void k_main(
    const float* __restrict__ heb, const unsigned short* __restrict__ hdb,
    const float* __restrict__ b2, const char* __restrict__ w2p,
    const float* __restrict__ scF, float* __restrict__ out)
{
    __shared__ uint4 ldsq[2048];          // 32 KB: raw hdb / hid_q / transpose
    __shared__ float redm[32][8];
    __shared__ float reds[32][8];
    char* lds = (char*)ldsq;

    // XCD-bijective remap (4096 % 8 == 0)
    const int bid = ((blockIdx.x & 7) << 9) | (blockIdx.x >> 3);
    const int tid = threadIdx.x;
    const int bm = bid >> 2, nq = bid & 3;
    const int b = bm >> 8;
    const int lane = tid & 63, w = tid >> 6;
    const int l5 = lane & 31, lh = lane >> 5;

    // ---- stage phase A: coalesced hdb rows -> raw LDS [32][1KB] (swizzled) ----
    {
        const unsigned short* src = hdb + (size_t)(b * 128 + nq * 32) * 512;
        #pragma unroll
        for (int i = 0; i < 4; ++i) {
            int o = tid * 4 + i;               // 0..2047 16B-chunks
            int row = o >> 6, c16 = o & 63;
            u16x8 v = *(const u16x8*)(src + row * 512 + c16 * 8);
            *(u16x8*)(lds + swz(row, c16 * 16)) = v;
        }
    }
    __syncthreads();

    // ---- stage phase B: read fragment slices, tanh+pack into regs ----
    i32x4 oq[2];
    {
        const float* ep = heb + (size_t)bm * 512;
        #pragma unroll
        for (int it = 0; it < 2; ++it) {
            int k0 = (w * 2 + it) * 32 + lh * 16;
            u16x8 hv0 = *(const u16x8*)(lds + swz(l5, k0 * 2));
            u16x8 hv1 = *(const u16x8*)(lds + swz(l5, k0 * 2 + 16));
            float4 e0 = *(const float4*)(ep + k0);
            float4 e1 = *(const float4*)(ep + k0 + 4);
            float4 e2 = *(const float4*)(ep + k0 + 8);
            float4 e3 = *(const float4*)(ep + k0 + 12);
            oq[it][0] = pack4(tanh_fast(bf2f(hv0[0]) + e0.x), tanh_fast(bf2f(hv0[1]) + e0.y),
                              tanh_fast(bf2f(hv0[2]) + e0.z), tanh_fast(bf2f(hv0[3]) + e0.w), 127.f);
            oq[it][1] = pack4(tanh_fast(bf2f(hv0[4]) + e1.x), tanh_fast(bf2f(hv0[5]) + e1.y),
                              tanh_fast(bf2f(hv0[6]) + e1.z), tanh_fast(bf2f(hv0[7]) + e1.w), 127.f);
            oq[it][2] = pack4(tanh_fast(bf2f(hv1[0]) + e2.x), tanh_fast(bf2f(hv1[1]) + e2.y),
                              tanh_fast(bf2f(hv1[2]) + e2.z), tanh_fast(bf2f(hv1[3]) + e2.w), 127.f);
            oq[it][3] = pack4(tanh_fast(bf2f(hv1[4]) + e3.x), tanh_fast(bf2f(hv1[5]) + e3.y),
                              tanh_fast(bf2f(hv1[6]) + e3.z), tanh_fast(bf2f(hv1[7]) + e3.w), 127.f);
        }
    }
    __syncthreads();

    // ---- stage phase C: write hid_q frag-linear (16 KB) ----
    #pragma unroll
    for (int it = 0; it < 2; ++it)
        *(i32x4*)(lds + (w * 2 + it) * 1024 + lane * 16) = oq[it];
    __syncthreads();

    // ---- K-loop: w2 (A) from L2, 2-deep slot-reuse prefetch; hid_q (B) LDS ----
    const char* pw = w2p + ((size_t)w << 16) + (lane << 4);
    const char* la = lds + (lane << 4);

    i32x16 acc[4];
    #pragma unroll
    for (int ct = 0; ct < 4; ct++)
        #pragma unroll
        for (int r = 0; r < 16; r++)
            acc[ct][r] = 0;

    i32x4 aw[2][4];
    #pragma unroll
    for (int ct = 0; ct < 4; ct++) {
        aw[0][ct] = *(const i32x4*)(pw + ct * 16384);
        aw[1][ct] = *(const i32x4*)(pw + ct * 16384 + 1024);
    }
    i32x4 h0 = *(const i32x4*)(la);

    #pragma unroll
    for (int kt = 0; kt < 16; ++kt) {
        i32x4 hn = h0;
        if (kt < 15) hn = *(const i32x4*)(la + (kt + 1) * 1024);
        __builtin_amdgcn_s_setprio(1);
        #pragma unroll
        for (int ct = 0; ct < 4; ct++)
            acc[ct] = __builtin_amdgcn_mfma_i32_32x32x32_i8(aw[kt & 1][ct], h0, acc[ct], 0, 0, 0);
        __builtin_amdgcn_s_setprio(0);
        if (kt < 14) {
            #pragma unroll
            for (int ct = 0; ct < 4; ct++)
                aw[kt & 1][ct] = *(const i32x4*)(pw + ct * 16384 + (kt + 2) * 1024);
        }
        h0 = hn;
    }

    // ---- dequant + b2, f32 bits written back in place ----
    #pragma unroll
    for (int ct = 0; ct < 4; ct++)
        #pragma unroll
        for (int q = 0; q < 4; q++) {
            const int base = w * 128 + ct * 32 + q * 8 + lh * 4;
            float4 sc4 = *(const float4*)(scF + base);
            float4 b24 = *(const float4*)(b2 + base);
            acc[ct][q * 4 + 0] = __float_as_int((float)acc[ct][q * 4 + 0] * sc4.x + b24.x);
            acc[ct][q * 4 + 1] = __float_as_int((float)acc[ct][q * 4 + 1] * sc4.y + b24.y);
            acc[ct][q * 4 + 2] = __float_as_int((float)acc[ct][q * 4 + 2] * sc4.z + b24.z);
            acc[ct][q * 4 + 3] = __float_as_int((float)acc[ct][q * 4 + 3] * sc4.w + b24.w);
        }

    // ---- row stats: 64 values in-lane (row n = l5), merge lane^32 ----
    float mx = -3.4e38f;
    #pragma unroll
    for (int ct = 0; ct < 4; ct++)
        #pragma unroll
        for (int r = 0; r < 16; r++)
            mx = fmaxf(mx, __int_as_float(acc[ct][r]));
    float sv = 0.f;
    #pragma unroll
    for (int ct = 0; ct < 4; ct++)
        #pragma unroll
        for (int r = 0; r < 16; r++)
            sv += __expf(__int_as_float(acc[ct][r]) - mx);
    {
        float mo = __shfl_xor(mx, 32), so = __shfl_xor(sv, 32);
        float mn = fmaxf(mx, mo);
        sv = sv * __expf(mx - mn) + so * __expf(mo - mn);
        mx = mn;
    }
    if (lh == 0) { redm[l5][w] = mx; reds[l5][w] = sv; }
    __syncthreads();   // hid LDS dead after this -> reuse for transpose

    float logZ;
    {
        float4 ma = *(const float4*)&redm[l5][0];
        float4 mb = *(const float4*)&redm[l5][4];
        float4 sa = *(const float4*)&reds[l5][0];
        float4 sb = *(const float4*)&reds[l5][4];
        float M = fmaxf(fmaxf(fmaxf(ma.x, ma.y), fmaxf(ma.z, ma.w)),
                        fmaxf(fmaxf(mb.x, mb.y), fmaxf(mb.z, mb.w)));
        float S = sa.x * __expf(ma.x - M) + sa.y * __expf(ma.y - M)
                + sa.z * __expf(ma.z - M) + sa.w * __expf(ma.w - M)
                + sb.x * __expf(mb.x - M) + sb.y * __expf(mb.y - M)
                + sb.z * __expf(mb.z - M) + sb.w * __expf(mb.w - M);
        logZ = M + __logf(S);
    }

    // ---- store epilogue: per-wave LDS transpose -> full-line nt stores ----
    char* myr = lds + w * 4096;
    const size_t rowbase = (size_t)bm * 128 + nq * 32;
    const int rr = lane >> 2, c4 = lane & 3;
    #pragma unroll
    for (int ct = 0; ct < 4; ct++) {
        #pragma unroll
        for (int q = 0; q < 4; q++) {
            f32x4 o;
            o[0] = __int_as_float(acc[ct][q * 4 + 0]) - logZ;
            o[1] = __int_as_float(acc[ct][q * 4 + 1]) - logZ;
            o[2] = __int_as_float(acc[ct][q * 4 + 2]) - logZ;
            o[3] = __int_as_float(acc[ct][q * 4 + 3]) - logZ;
            *(f32x4*)(myr + l5 * 128 + ((q * 32 + lh * 16) ^ ((l5 & 7) << 4))) = o;
        }
        #pragma unroll
        for (int rh = 0; rh < 2; rh++)
            #pragma unroll
            for (int chv = 0; chv < 2; chv++) {
                int row = rh * 16 + rr;
                f32x4 v = *(const f32x4*)(myr + row * 128 +
                                          ((chv * 64 + c4 * 16) ^ ((row & 7) << 4)));
                __builtin_nontemporal_store(v,
                    (f32x4*)(out + (rowbase + row) * 1024 + w * 128 + ct * 32 +
                             chv * 16 + c4 * 4));
            }
    }
}

extern "C" void kernel_launch(void* const* d_in, const int* in_sizes, int n_in,
                              void* d_out, int out_size, void* d_ws, size_t ws_size,
                              hipStream_t stream) {
    const float* enc = (const float*)d_in[0];
    const float* dec = (const float*)d_in[1];
    const float* w1  = (const float*)d_in[2];
    const float* b1  = (const float*)d_in[3];
    const float* w2  = (const float*)d_in[4];
    const float* b2  = (const float*)d_in[5];

    float* heb = (float*)d_ws;                                   // 2 MB
    unsigned short* hdb = (unsigned short*)(heb + 1024 * 512);   // 0.5 MB
    char* w2p = (char*)(hdb + 512 * 512);                        // 512 KB
    float* scF = (float*)(w2p + 512 * 1024);                     // 4 KB

    k_prep<<<128, 512, 0, stream>>>(enc, dec, w1, b1, w2, heb, hdb, w2p, scF);
    k_main<<<4096, 512, 0, stream>>>(heb, hdb, b2, w2p, scF, (float*)d_out);
}